// Round 3
// baseline (902.546 us; speedup 1.0000x reference)
//
#include <hip/hip_runtime.h>
#include <cstdint>
#include <cstddef>

typedef __bf16 bf16;
typedef __bf16 bf16x8 __attribute__((ext_vector_type(8)));
typedef float  f32x4  __attribute__((ext_vector_type(4)));

constexpr int S_      = 2048;
constexpr int H_      = 2048;
constexpr int NH_     = 16;
constexpr int KV_RANK_= 256;
constexpr int EXP_    = 8;
constexpr int INTER_  = 1408;
constexpr int QH_     = 128;
constexpr float EPS_  = 1e-6f;

__device__ inline void gload16(const void* g, void* l) {
  __builtin_amdgcn_global_load_lds(
      (const __attribute__((address_space(1))) void*)g,
      (__attribute__((address_space(3))) void*)l, 16, 0, 0);
}

enum { EPI_BF16 = 0, EPI_F32 = 1, EPI_ADD = 2, EPI_SILU = 3, EPI_ATOM = 4 };

// ---------------------------------------------------------------------------
// MFMA GEMM: C[M,N] (+)= A[M,K] @ B[N,K]^T   (BK=64, TILE in {64,128})
//  4 waves as 2x2, each wave (TILE/2)^2 via FRxFRx2 mfma_f32_16x16x32_bf16.
//  XOR-swizzled LDS (conflict-free), staging via global_load_lds width=16.
//  kPerE>0: flat-K MoE, B base hops every kPerE cols by bExpStride.
//  launch_bounds(256,5): LDS 32KB/block -> 5 blocks/CU (160KB); VGPR ~124
//  incl AGPR, far under the 5-wave/EU cap of ~409. TLP hides barrier drains.
// ---------------------------------------------------------------------------
template <int EPI, typename TB, int TILE>
__global__ void __launch_bounds__(256, 5) gemm_bt(
    const bf16* __restrict__ A, const TB* __restrict__ B,
    void* __restrict__ Cv, const float* __restrict__ aux,
    int M, int N, int K, int lda, int ldb, int ldc,
    long zA, long zB, long zC, long auxZ, int auxRS,
    int kPerE, long bExpStride, int expBasePerZ)
{
  constexpr int FR = TILE / 32;
  const int tileN = blockIdx.x * TILE;
  const int tileM = blockIdx.y * TILE;
  const int z = blockIdx.z;
  A += (long)z * zA;

  __shared__ __align__(16) bf16 As[TILE * 64];
  __shared__ __align__(16) TB   Bs[TILE * 64];
  char* AsB = (char*)As;
  char* BsB = (char*)Bs;

  const int tid  = threadIdx.x;
  const int lane = tid & 63;
  const int wave = tid >> 6;
  const int wr = wave >> 1, wc = wave & 1;
  const int quad = lane >> 4, r16 = lane & 15;

  const int ldbe = (kPerE > 0) ? kPerE : ldb;
  const TB* BzBase = (kPerE > 0) ? (B + (long)z * expBasePerZ * bExpStride)
                                 : (B + (long)z * zB);

  constexpr int IA = TILE / 32;
  const bf16* aG[IA]; char* aL[IA];
#pragma unroll
  for (int i = 0; i < IA; i++) {
    int n = (wave * IA + i) * 64 + lane;
    int row = n >> 3, cp = n & 7;
    int cc = (cp ^ (row & 7)) << 3;
    int rowg = tileM + row; if (rowg > M - 1) rowg = M - 1;
    aG[i] = A + (long)rowg * lda + cc;
    aL[i] = AsB + (long)(wave * IA + i) * 1024;
  }
  constexpr int IB = (sizeof(TB) == 4) ? (TILE / 16) : (TILE / 32);
  const TB* bG[IB]; char* bL[IB];
#pragma unroll
  for (int i = 0; i < IB; i++) {
    int n = (wave * IB + i) * 64 + lane;
    int row, cc;
    if constexpr (sizeof(TB) == 4) { row = n >> 4; cc = ((n & 15) ^ (row & 15)) << 2; }
    else                           { row = n >> 3; cc = ((n & 7)  ^ (row & 7))  << 3; }
    int rowg = tileN + row; if (rowg > N - 1) rowg = N - 1;
    bG[i] = BzBase + (long)rowg * ldbe + cc;
    bL[i] = BsB + (long)(wave * IB + i) * 1024;
  }

  int aOff[FR], bOff[FR];
#pragma unroll
  for (int i = 0; i < FR; i++) {
    int row = wr * (TILE / 2) + i * 16 + r16;
    aOff[i] = row * 128 + ((quad ^ (row & 7)) << 4);
  }
#pragma unroll
  for (int j = 0; j < FR; j++) {
    int row = wc * (TILE / 2) + j * 16 + r16;
    if constexpr (sizeof(TB) == 4) bOff[j] = row * 256 + (((2 * quad) ^ (row & 15)) << 4);
    else                           bOff[j] = row * 128 + ((quad ^ (row & 7)) << 4);
  }

  f32x4 acc[FR][FR];
#pragma unroll
  for (int i = 0; i < FR; i++)
#pragma unroll
    for (int j = 0; j < FR; j++)
#pragma unroll
      for (int r = 0; r < 4; r++) acc[i][j][r] = 0.f;

  int bk = 0; long eOff = 0;
  for (int k0 = 0; k0 < K; k0 += 64) {
#pragma unroll
    for (int i = 0; i < IA; i++) gload16(aG[i] + k0, aL[i]);
#pragma unroll
    for (int i = 0; i < IB; i++) gload16(bG[i] + eOff + bk, bL[i]);
    __syncthreads();

#pragma unroll
    for (int s = 0; s < 2; s++) {
      bf16x8 af[FR], bfv[FR];
#pragma unroll
      for (int i = 0; i < FR; i++)
        af[i] = *(const bf16x8*)(AsB + (aOff[i] ^ (s << 6)));
#pragma unroll
      for (int j = 0; j < FR; j++) {
        if constexpr (sizeof(TB) == 2) {
          bfv[j] = *(const bf16x8*)(BsB + (bOff[j] ^ (s << 6)));
        } else {
          int a0 = bOff[j] ^ (s << 7);
          f32x4 lo = *(const f32x4*)(BsB + a0);
          f32x4 hi = *(const f32x4*)(BsB + (a0 ^ 16));
          bf16x8 v;
          v[0]=(bf16)lo[0]; v[1]=(bf16)lo[1]; v[2]=(bf16)lo[2]; v[3]=(bf16)lo[3];
          v[4]=(bf16)hi[0]; v[5]=(bf16)hi[1]; v[6]=(bf16)hi[2]; v[7]=(bf16)hi[3];
          bfv[j] = v;
        }
      }
#pragma unroll
      for (int i = 0; i < FR; i++)
#pragma unroll
        for (int j = 0; j < FR; j++)
          acc[i][j] = __builtin_amdgcn_mfma_f32_16x16x32_bf16(af[i], bfv[j], acc[i][j], 0, 0, 0);
    }
    __syncthreads();

    bk += 64;
    if (kPerE > 0 && bk >= kPerE) { bk = 0; eOff += bExpStride; }
  }

  bf16*  Cb = (bf16*)Cv + (long)z * zC;
  float* Cf = (float*)Cv + (long)z * zC;
  const float* auxp = aux + (long)z * auxZ;
  const int mB = tileM + wr * (TILE / 2) + quad * 4;
  const int nB = tileN + wc * (TILE / 2) + r16;
#pragma unroll
  for (int i = 0; i < FR; i++) {
#pragma unroll
    for (int r = 0; r < 4; r++) {
      int gm = mB + i * 16 + r;
      if (gm >= M) continue;
      float rowAux = 0.f;
      if constexpr (EPI == EPI_SILU) rowAux = auxp[(long)gm * auxRS];
#pragma unroll
      for (int j = 0; j < FR; j++) {
        int gn = nB + j * 16;
        if (gn >= N) continue;
        float v = acc[i][j][r];
        long off = (long)gm * ldc + gn;
        if constexpr (EPI == EPI_BF16)      Cb[off] = (bf16)v;
        else if constexpr (EPI == EPI_F32)  Cf[off] = v;
        else if constexpr (EPI == EPI_ADD)  Cf[off] = auxp[(long)gm * auxRS + gn] + v;
        else if constexpr (EPI == EPI_SILU) { float sv = v / (1.f + __expf(-v)); Cb[off] = (bf16)(sv * rowAux); }
        else                                atomicAdd(&Cf[off], v);
      }
    }
  }
}

// ---------------------------------------------------------------------------
// Flash attention (causal): Q,K [NH][S][128], V^T [NH][64][S] -> ctx [S][NH*64]
// grid (NH, S/64); 4 waves, wave w owns q-rows qt*64+w*16..+15.
// ---------------------------------------------------------------------------
__global__ void __launch_bounds__(256) flash_k(
    const bf16* __restrict__ q, const bf16* __restrict__ k,
    const bf16* __restrict__ vt, bf16* __restrict__ ctx, float scale)
{
  const int h  = blockIdx.x;
  const int qt = (int)gridDim.y - 1 - (int)blockIdx.y;   // long blocks first
  const int tid = threadIdx.x, lane = tid & 63, wave = tid >> 6;
  const int quad = lane >> 4, r16 = lane & 15;

  __shared__ __align__(16) bf16 Ks[64 * 128];   // [key][d]  16-chunk swizzle
  __shared__ __align__(16) bf16 Vs[64 * 64];    // [d][key]   8-chunk swizzle
  __shared__ __align__(16) bf16 Ps[4][16 * 64]; // per-wave P, 8-chunk swizzle
  char* KsB = (char*)Ks;
  char* VsB = (char*)Vs;
  char* PsB = (char*)&Ps[wave][0];

  bf16x8 qf[4];
  {
    const bf16* qp = q + ((long)h * S_ + qt * 64 + wave * 16 + r16) * 128 + quad * 8;
#pragma unroll
    for (int ks = 0; ks < 4; ks++) qf[ks] = *(const bf16x8*)(qp + ks * 32);
  }

  const bf16* kG[4]; char* kL[4];
#pragma unroll
  for (int i = 0; i < 4; i++) {
    int n = (wave * 4 + i) * 64 + lane;
    int row = n >> 4, c = n & 15;
    kG[i] = k + ((long)h * S_ + row) * 128 + ((c ^ (row & 15)) << 3);
    kL[i] = KsB + (long)(wave * 4 + i) * 1024;
  }
  const bf16* vG[2]; char* vL[2];
#pragma unroll
  for (int i = 0; i < 2; i++) {
    int n = (wave * 2 + i) * 64 + lane;
    int row = n >> 3, c = n & 7;
    vG[i] = vt + ((long)h * 64 + row) * S_ + ((c ^ (row & 7)) << 3);
    vL[i] = VsB + (long)(wave * 2 + i) * 1024;
  }

  float mr[4], lr[4];
#pragma unroll
  for (int r = 0; r < 4; r++) { mr[r] = -1e30f; lr[r] = 0.f; }
  f32x4 o[4];
#pragma unroll
  for (int j = 0; j < 4; j++)
#pragma unroll
    for (int r = 0; r < 4; r++) o[j][r] = 0.f;

  for (int kt = 0; kt <= qt; kt++) {
#pragma unroll
    for (int i = 0; i < 4; i++) gload16(kG[i] + (long)kt * 64 * 128, kL[i]);
#pragma unroll
    for (int i = 0; i < 2; i++) gload16(vG[i] + kt * 64, vL[i]);
    __syncthreads();

    f32x4 s[4];
#pragma unroll
    for (int j = 0; j < 4; j++)
#pragma unroll
      for (int r = 0; r < 4; r++) s[j][r] = 0.f;
#pragma unroll
    for (int ks = 0; ks < 4; ks++) {
#pragma unroll
      for (int j = 0; j < 4; j++) {
        int row = j * 16 + r16;
        int c = ks * 4 + quad;
        bf16x8 bfr = *(const bf16x8*)(KsB + row * 256 + ((c ^ (row & 15)) << 4));
        s[j] = __builtin_amdgcn_mfma_f32_16x16x32_bf16(qf[ks], bfr, s[j], 0, 0, 0);
      }
    }

    if (kt == qt) {
#pragma unroll
      for (int j = 0; j < 4; j++)
#pragma unroll
        for (int r = 0; r < 4; r++)
          if (j * 16 + r16 > wave * 16 + quad * 4 + r) s[j][r] = -1e30f;
    }

    float pj[4][4];
#pragma unroll
    for (int r = 0; r < 4; r++) {
      float mx = fmaxf(fmaxf(s[0][r], s[1][r]), fmaxf(s[2][r], s[3][r]));
#pragma unroll
      for (int off = 1; off < 16; off <<= 1) mx = fmaxf(mx, __shfl_xor(mx, off, 64));
      mx *= scale;
      float nm = fmaxf(mr[r], mx);
      float alpha = __expf(mr[r] - nm);
      mr[r] = nm;
      float rs = 0.f;
#pragma unroll
      for (int j = 0; j < 4; j++) { float e = __expf(s[j][r] * scale - nm); pj[j][r] = e; rs += e; }
#pragma unroll
      for (int off = 1; off < 16; off <<= 1) rs += __shfl_xor(rs, off, 64);
      lr[r] = lr[r] * alpha + rs;
#pragma unroll
      for (int j = 0; j < 4; j++) o[j][r] *= alpha;
    }

#pragma unroll
    for (int j = 0; j < 4; j++) {
      int chunk = j * 2 + (r16 >> 3);
#pragma unroll
      for (int r = 0; r < 4; r++) {
        int row = quad * 4 + r;
        *(bf16*)(PsB + row * 128 + ((chunk ^ (row & 7)) << 4) + ((r16 & 7) << 1)) = (bf16)pj[j][r];
      }
    }

#pragma unroll
    for (int ks = 0; ks < 2; ks++) {
      int c = ks * 4 + quad;
      bf16x8 af = *(const bf16x8*)(PsB + r16 * 128 + ((c ^ (r16 & 7)) << 4));
#pragma unroll
      for (int j = 0; j < 4; j++) {
        int row = j * 16 + r16;
        bf16x8 bfr = *(const bf16x8*)(VsB + row * 128 + ((c ^ (row & 7)) << 4));
        o[j] = __builtin_amdgcn_mfma_f32_16x16x32_bf16(af, bfr, o[j], 0, 0, 0);
      }
    }
    __syncthreads();
  }

  bf16* cp = ctx + ((long)(qt * 64 + wave * 16 + quad * 4)) * (NH_ * 64) + h * 64 + r16;
#pragma unroll
  for (int r = 0; r < 4; r++) {
    float rl = 1.f / lr[r];
#pragma unroll
    for (int j = 0; j < 4; j++)
      cp[(long)r * NH_ * 64 + j * 16] = (bf16)(o[j][r] * rl);
  }
}

// ---------------------------------------------------------------------------
template <int NIT>
__global__ void __launch_bounds__(256) rmsnorm_k(
    const float* __restrict__ x, const float* __restrict__ w,
    bf16* __restrict__ out, int inStride)
{
  const int row = blockIdx.x, tid = threadIdx.x;
  const float* xr = x + (long)row * inStride;
  float vals[NIT];
  float ss = 0.f;
#pragma unroll
  for (int i = 0; i < NIT; i++) { float v = xr[i * 256 + tid]; vals[i] = v; ss += v * v; }
#pragma unroll
  for (int o = 32; o; o >>= 1) ss += __shfl_xor(ss, o, 64);
  __shared__ float red[4];
  if ((tid & 63) == 0) red[tid >> 6] = ss;
  __syncthreads();
  ss = red[0] + red[1] + red[2] + red[3];
  const float rinv = rsqrtf(ss / (float)(NIT * 256) + EPS_);
  bf16* orow = out + (long)row * (NIT * 256);
#pragma unroll
  for (int i = 0; i < NIT; i++) { int c = i * 256 + tid; orow[c] = (bf16)(w[c] * vals[i] * rinv); }
}

// ---------------------------------------------------------------------------
__global__ void prep_qkv_k(const bf16* __restrict__ q, const bf16* __restrict__ kv,
                           const float* __restrict__ ckv, const int* __restrict__ pos,
                           bf16* __restrict__ query, bf16* __restrict__ key,
                           bf16* __restrict__ vvT)
{
  const int s = blockIdx.x, h = blockIdx.y, d = threadIdx.x;
  const long qkOff = ((long)h * S_ + s) * QH_ + d;
  if (d < 64) {
    query[qkOff] = q[(long)s * H_ + h * QH_ + d];
    key[qkOff]   = kv[(long)s * H_ + h * QH_ + d];
    vvT[((long)h * 64 + d) * S_ + s] = kv[(long)s * H_ + h * QH_ + 64 + d];
  } else {
    const int i = d - 64;
    const float p = (float)pos[s];
    const float invf = powf(10000.f, -(float)(2 * (i & 31)) / 64.f);
    const float ang = p * invf;
    const float cc = cosf(ang), sn = sinf(ang);
    const float xq  = (float)q[(long)s * H_ + h * QH_ + 64 + i];
    const float xqr = (i < 32) ? -(float)q[(long)s * H_ + h * QH_ + 64 + i + 32]
                               :  (float)q[(long)s * H_ + h * QH_ + 64 + i - 32];
    query[qkOff] = (bf16)(xq * cc + xqr * sn);
    const float xk  = ckv[(long)s * 320 + 256 + i];
    const float xkr = (i < 32) ? -ckv[(long)s * 320 + 256 + i + 32]
                               :  ckv[(long)s * 320 + 256 + i - 32];
    key[qkOff] = (bf16)(xk * cc + xkr * sn);
  }
}

// ---------------------------------------------------------------------------
__global__ void __launch_bounds__(256) gate_k(const bf16* __restrict__ mlp,
                                              const float* __restrict__ gw,
                                              float* __restrict__ probs)
{
  const int s = blockIdx.x, tid = threadIdx.x;
  float acc[8];
#pragma unroll
  for (int e = 0; e < 8; e++) acc[e] = 0.f;
  for (int c = tid; c < H_; c += 256) {
    float x = (float)mlp[(long)s * H_ + c];
#pragma unroll
    for (int e = 0; e < 8; e++) acc[e] += x * gw[e * H_ + c];
  }
  __shared__ float red[4][8];
#pragma unroll
  for (int e = 0; e < 8; e++) {
    float v = acc[e];
#pragma unroll
    for (int o = 32; o; o >>= 1) v += __shfl_xor(v, o, 64);
    if ((tid & 63) == 0) red[tid >> 6][e] = v;
  }
  __syncthreads();
  if (tid == 0) {
    float l[8]; float mx = -1e30f;
#pragma unroll
    for (int e = 0; e < 8; e++) { l[e] = red[0][e] + red[1][e] + red[2][e] + red[3][e]; mx = fmaxf(mx, l[e]); }
    float sum = 0.f;
#pragma unroll
    for (int e = 0; e < 8; e++) { l[e] = __expf(l[e] - mx); sum += l[e]; }
    float r = 1.f / sum;
#pragma unroll
    for (int e = 0; e < 8; e++) probs[(long)s * 8 + e] = l[e] * r;
  }
}

// ---------------------------------------------------------------------------
__global__ void __launch_bounds__(256) wconv_k(const float* __restrict__ in,
                                               bf16* __restrict__ out, int n8)
{
  int i = blockIdx.x * 256 + threadIdx.x;
  if (i < n8) {
    f32x4 a = ((const f32x4*)in)[2 * i];
    f32x4 b = ((const f32x4*)in)[2 * i + 1];
    bf16x8 v;
    v[0] = (bf16)a[0]; v[1] = (bf16)a[1]; v[2] = (bf16)a[2]; v[3] = (bf16)a[3];
    v[4] = (bf16)b[0]; v[5] = (bf16)b[1]; v[6] = (bf16)b[2]; v[7] = (bf16)b[3];
    ((bf16x8*)out)[i] = v;
  }
}

// ---------------------------------------------------------------------------
extern "C" void kernel_launch(void* const* d_in, const int* in_sizes, int n_in,
                              void* d_out, int out_size, void* d_ws, size_t ws_size,
                              hipStream_t stream)
{
  const int*   positions = (const int*)  d_in[0];
  const float* hidden    = (const float*)d_in[1];
  const float* ln1       = (const float*)d_in[2];
  const float* wq        = (const float*)d_in[3];
  const float* wkva      = (const float*)d_in[4];
  const float* lnkv      = (const float*)d_in[5];
  const float* wkvb      = (const float*)d_in[6];
  const float* wo        = (const float*)d_in[7];
  const float* ln2       = (const float*)d_in[8];
  const float* wg        = (const float*)d_in[9];
  const float* wfc1      = (const float*)d_in[10];
  const float* wfc2      = (const float*)d_in[11];
  float* out = (float*)d_out;

  char* wsb = (char*)d_ws;
  size_t off = 0;
  auto alloc = [&](size_t bytes) -> void* {
    void* p = wsb + off;
    off += (bytes + 255) & ~(size_t)255;
    return p;
  };
  bf16*  sa_in = (bf16*) alloc((size_t)S_ * H_ * 2);
  bf16*  qb    = (bf16*) alloc((size_t)S_ * H_ * 2);
  float* ckv   = (float*)alloc((size_t)S_ * 320 * 4);
  bf16*  ckvn  = (bf16*) alloc((size_t)S_ * KV_RANK_ * 2);
  bf16*  kvb   = (bf16*) alloc((size_t)S_ * H_ * 2);
  bf16*  query = (bf16*) alloc((size_t)NH_ * S_ * QH_ * 2);
  bf16*  key   = (bf16*) alloc((size_t)NH_ * S_ * QH_ * 2);
  bf16*  vvT   = (bf16*) alloc((size_t)NH_ * 64 * S_ * 2);
  bf16*  ctx   = (bf16*) alloc((size_t)S_ * NH_ * 64 * 2);
  bf16*  mlp   = (bf16*) alloc((size_t)S_ * H_ * 2);
  float* probs = (float*)alloc((size_t)S_ * 8 * 4);
  bf16*  hbuf  = (bf16*) alloc((size_t)S_ * EXP_ * INTER_ * 2);

  const size_t MBy = (size_t)1 << 20;
  const size_t rem = (ws_size > off) ? ws_size - off : 0;
  const size_t szMoeW = (size_t)EXP_ * INTER_ * H_ * 2;      // 46.1 MB each
  const bool cw = (rem >= 93 * MBy);

  bf16* fc1b = nullptr; bf16* fc2b = nullptr;
  if (cw) { fc1b = (bf16*)alloc(szMoeW); fc2b = (bf16*)alloc(szMoeW); }
  // attention weights (bf16) alias hbuf (dead until fc1; o_proj finishes first)
  bf16* wqb   = (bf16*)hbuf;
  bf16* wkvab = wqb   + (size_t)H_ * H_;
  bf16* wkvbb = wkvab + (size_t)320 * H_;
  bf16* wob   = wkvbb + (size_t)H_ * KV_RANK_;

  const float scale = 0.08838834764831845f;   // 128^-0.5

  rmsnorm_k<8><<<S_, 256, 0, stream>>>(hidden, ln1, sa_in, H_);

  if (cw) {
    wconv_k<<<(H_*H_/8 + 255)/256, 256, 0, stream>>>(wq, wqb, H_*H_/8);
    wconv_k<<<(320*H_/8 + 255)/256, 256, 0, stream>>>(wkva, wkvab, 320*H_/8);
    wconv_k<<<(H_*KV_RANK_/8 + 255)/256, 256, 0, stream>>>(wkvb, wkvbb, H_*KV_RANK_/8);
    wconv_k<<<(H_*NH_*64/8 + 255)/256, 256, 0, stream>>>(wo, wob, H_*NH_*64/8);
    wconv_k<<<(EXP_*INTER_*H_/8 + 255)/256, 256, 0, stream>>>(wfc1, fc1b, EXP_*INTER_*H_/8);
    wconv_k<<<(EXP_*INTER_*H_/8 + 255)/256, 256, 0, stream>>>(wfc2, fc2b, EXP_*INTER_*H_/8);
  }

  // q_proj [2048x2048, K=2048]
  if (cw) gemm_bt<EPI_BF16, bf16, 64><<<dim3(32,32,1), 256, 0, stream>>>(
      sa_in, wqb, qb, hidden, S_, H_, H_, H_, H_, H_, 0,0,0,0,0, 0,0,0);
  else    gemm_bt<EPI_BF16, float, 64><<<dim3(32,32,1), 256, 0, stream>>>(
      sa_in, wq,  qb, hidden, S_, H_, H_, H_, H_, H_, 0,0,0,0,0, 0,0,0);

  // kv_a [2048x320, K=2048] -> fp32
  if (cw) gemm_bt<EPI_F32, bf16, 64><<<dim3(5,32,1), 256, 0, stream>>>(
      sa_in, wkvab, ckv, hidden, S_, 320, H_, H_, H_, 320, 0,0,0,0,0, 0,0,0);
  else    gemm_bt<EPI_F32, float, 64><<<dim3(5,32,1), 256, 0, stream>>>(
      sa_in, wkva,  ckv, hidden, S_, 320, H_, H_, H_, 320, 0,0,0,0,0, 0,0,0);

  rmsnorm_k<1><<<S_, 256, 0, stream>>>(ckv, lnkv, ckvn, 320);

  // kv_b [2048x2048, K=256]
  if (cw) gemm_bt<EPI_BF16, bf16, 64><<<dim3(32,32,1), 256, 0, stream>>>(
      ckvn, wkvbb, kvb, hidden, S_, H_, KV_RANK_, KV_RANK_, KV_RANK_, H_, 0,0,0,0,0, 0,0,0);
  else    gemm_bt<EPI_BF16, float, 64><<<dim3(32,32,1), 256, 0, stream>>>(
      ckvn, wkvb,  kvb, hidden, S_, H_, KV_RANK_, KV_RANK_, KV_RANK_, H_, 0,0,0,0,0, 0,0,0);

  prep_qkv_k<<<dim3(S_, NH_), 128, 0, stream>>>(qb, kvb, ckv, positions, query, key, vvT);

  // fused causal attention -> ctx
  flash_k<<<dim3(NH_, S_/64), 256, 0, stream>>>(query, key, vvT, ctx, scale);

  // o_proj: out = hidden + ctx @ wo^T   (writes d_out directly)
  if (cw) gemm_bt<EPI_ADD, bf16, 64><<<dim3(32,32,1), 256, 0, stream>>>(
      ctx, wob, out, hidden, S_, H_, NH_*64, NH_*64, NH_*64, H_, 0,0,0,0, H_, 0,0,0);
  else    gemm_bt<EPI_ADD, float, 64><<<dim3(32,32,1), 256, 0, stream>>>(
      ctx, wo,  out, hidden, S_, H_, NH_*64, NH_*64, NH_*64, H_, 0,0,0,0, H_, 0,0,0);

  rmsnorm_k<8><<<S_, 256, 0, stream>>>(out, ln2, mlp, H_);
  gate_k<<<S_, 256, 0, stream>>>(mlp, wg, probs);

  // fc1: hbuf[s][e*1408+i] = silu(mlp @ fc1_w[e]^T) * probs[s][e]
  if (cw) gemm_bt<EPI_SILU, bf16, 128><<<dim3(11,16,8), 256, 0, stream>>>(
      mlp, fc1b, hbuf, probs, S_, INTER_, H_, H_, H_, EXP_*INTER_,
      0, (long)INTER_*H_, INTER_, 1, 8, 0, 0, 0);
  else    gemm_bt<EPI_SILU, float, 128><<<dim3(11,16,8), 256, 0, stream>>>(
      mlp, wfc1, hbuf, probs, S_, INTER_, H_, H_, H_, EXP_*INTER_,
      0, (long)INTER_*H_, INTER_, 1, 8, 0, 0, 0);

  // fc2: z=4, each z covers 2 experts flat-K (K=2816, kPerE hop), atomicAdd
  // fp32 into out.
  if (cw) gemm_bt<EPI_ATOM, bf16, 128><<<dim3(16,16,4), 256, 0, stream>>>(
      hbuf, fc2b, out, hidden, S_, H_, 2*INTER_, EXP_*INTER_, 0, H_,
      (long)(2*INTER_), 0, 0, 0, 0, INTER_, (long)H_*INTER_, 2);
  else    gemm_bt<EPI_ATOM, float, 128><<<dim3(16,16,4), 256, 0, stream>>>(
      hbuf, wfc2, out, hidden, S_, H_, 2*INTER_, EXP_*INTER_, 0, H_,
      (long)(2*INTER_), 0, 0, 0, 0, INTER_, (long)H_*INTER_, 2);
}

// Round 4
// 686.678 us; speedup vs baseline: 1.3144x; 1.3144x over previous
//
#include <hip/hip_runtime.h>
#include <cstdint>
#include <cstddef>

typedef __bf16 bf16;
typedef __bf16 bf16x8 __attribute__((ext_vector_type(8)));
typedef float  f32x4  __attribute__((ext_vector_type(4)));

constexpr int S_      = 2048;
constexpr int H_      = 2048;
constexpr int NH_     = 16;
constexpr int KV_RANK_= 256;
constexpr int EXP_    = 8;
constexpr int INTER_  = 1408;
constexpr int QH_     = 128;
constexpr float EPS_  = 1e-6f;

__device__ inline void gload16(const void* g, void* l) {
  __builtin_amdgcn_global_load_lds(
      (const __attribute__((address_space(1))) void*)g,
      (__attribute__((address_space(3))) void*)l, 16, 0, 0);
}

enum { EPI_BF16 = 0, EPI_F32 = 1, EPI_ADD = 2, EPI_SILU = 3, EPI_ATOM = 4 };

// ---------------------------------------------------------------------------
// MFMA GEMM: C[M,N] (+)= A[M,K] @ B[N,K]^T   (BK=64, TILE in {64,128})
//  4 waves as 2x2, each wave (TILE/2)^2 via FRxFRx2 mfma_f32_16x16x32_bf16.
//  XOR-swizzled LDS (conflict-free), staging via global_load_lds width=16.
//  kPerE>0: flat-K MoE, B base hops every kPerE cols by bExpStride.
//  launch_bounds(256,3): 60 VGPR + 64 AGPR fits 4 waves/EU; declaring 5
//  squeezed the allocator to 48 VGPR and cost 75% on fc1 (round-3 lesson).
//  XSWZ=1: XCD-chunked bijective remap (requires nwg%8==0) so each XCD's
//  private L2 sees one contiguous work chunk (one expert for fc1).
// ---------------------------------------------------------------------------
template <int EPI, typename TB, int TILE, int XSWZ = 0>
__global__ void __launch_bounds__(256, 3) gemm_bt(
    const bf16* __restrict__ A, const TB* __restrict__ B,
    void* __restrict__ Cv, const float* __restrict__ aux,
    int M, int N, int K, int lda, int ldb, int ldc,
    long zA, long zB, long zC, long auxZ, int auxRS,
    int kPerE, long bExpStride, int expBasePerZ)
{
  constexpr int FR = TILE / 32;
  int bx = blockIdx.x, by = blockIdx.y, bz = blockIdx.z;
  if constexpr (XSWZ) {
    const int gx = (int)gridDim.x, gy = (int)gridDim.y;
    const int nwg = gx * gy * (int)gridDim.z;
    int lin = (bz * gy + by) * gx + bx;
    const int cpx = nwg >> 3;
    int w = (lin & 7) * cpx + (lin >> 3);
    bx = w % gx; w /= gx;
    by = w % gy; bz = w / gy;
  }
  const int tileN = bx * TILE;
  const int tileM = by * TILE;
  const int z = bz;
  A += (long)z * zA;

  __shared__ __align__(16) bf16 As[TILE * 64];
  __shared__ __align__(16) TB   Bs[TILE * 64];
  char* AsB = (char*)As;
  char* BsB = (char*)Bs;

  const int tid  = threadIdx.x;
  const int lane = tid & 63;
  const int wave = tid >> 6;
  const int wr = wave >> 1, wc = wave & 1;
  const int quad = lane >> 4, r16 = lane & 15;

  const int ldbe = (kPerE > 0) ? kPerE : ldb;
  const TB* BzBase = (kPerE > 0) ? (B + (long)z * expBasePerZ * bExpStride)
                                 : (B + (long)z * zB);

  constexpr int IA = TILE / 32;
  const bf16* aG[IA]; char* aL[IA];
#pragma unroll
  for (int i = 0; i < IA; i++) {
    int n = (wave * IA + i) * 64 + lane;
    int row = n >> 3, cp = n & 7;
    int cc = (cp ^ (row & 7)) << 3;
    int rowg = tileM + row; if (rowg > M - 1) rowg = M - 1;
    aG[i] = A + (long)rowg * lda + cc;
    aL[i] = AsB + (long)(wave * IA + i) * 1024;
  }
  constexpr int IB = (sizeof(TB) == 4) ? (TILE / 16) : (TILE / 32);
  const TB* bG[IB]; char* bL[IB];
#pragma unroll
  for (int i = 0; i < IB; i++) {
    int n = (wave * IB + i) * 64 + lane;
    int row, cc;
    if constexpr (sizeof(TB) == 4) { row = n >> 4; cc = ((n & 15) ^ (row & 15)) << 2; }
    else                           { row = n >> 3; cc = ((n & 7)  ^ (row & 7))  << 3; }
    int rowg = tileN + row; if (rowg > N - 1) rowg = N - 1;
    bG[i] = BzBase + (long)rowg * ldbe + cc;
    bL[i] = BsB + (long)(wave * IB + i) * 1024;
  }

  int aOff[FR], bOff[FR];
#pragma unroll
  for (int i = 0; i < FR; i++) {
    int row = wr * (TILE / 2) + i * 16 + r16;
    aOff[i] = row * 128 + ((quad ^ (row & 7)) << 4);
  }
#pragma unroll
  for (int j = 0; j < FR; j++) {
    int row = wc * (TILE / 2) + j * 16 + r16;
    if constexpr (sizeof(TB) == 4) bOff[j] = row * 256 + (((2 * quad) ^ (row & 15)) << 4);
    else                           bOff[j] = row * 128 + ((quad ^ (row & 7)) << 4);
  }

  f32x4 acc[FR][FR];
#pragma unroll
  for (int i = 0; i < FR; i++)
#pragma unroll
    for (int j = 0; j < FR; j++)
#pragma unroll
      for (int r = 0; r < 4; r++) acc[i][j][r] = 0.f;

  int bk = 0; long eOff = 0;
  for (int k0 = 0; k0 < K; k0 += 64) {
#pragma unroll
    for (int i = 0; i < IA; i++) gload16(aG[i] + k0, aL[i]);
#pragma unroll
    for (int i = 0; i < IB; i++) gload16(bG[i] + eOff + bk, bL[i]);
    __syncthreads();

#pragma unroll
    for (int s = 0; s < 2; s++) {
      bf16x8 af[FR], bfv[FR];
#pragma unroll
      for (int i = 0; i < FR; i++)
        af[i] = *(const bf16x8*)(AsB + (aOff[i] ^ (s << 6)));
#pragma unroll
      for (int j = 0; j < FR; j++) {
        if constexpr (sizeof(TB) == 2) {
          bfv[j] = *(const bf16x8*)(BsB + (bOff[j] ^ (s << 6)));
        } else {
          int a0 = bOff[j] ^ (s << 7);
          f32x4 lo = *(const f32x4*)(BsB + a0);
          f32x4 hi = *(const f32x4*)(BsB + (a0 ^ 16));
          bf16x8 v;
          v[0]=(bf16)lo[0]; v[1]=(bf16)lo[1]; v[2]=(bf16)lo[2]; v[3]=(bf16)lo[3];
          v[4]=(bf16)hi[0]; v[5]=(bf16)hi[1]; v[6]=(bf16)hi[2]; v[7]=(bf16)hi[3];
          bfv[j] = v;
        }
      }
#pragma unroll
      for (int i = 0; i < FR; i++)
#pragma unroll
        for (int j = 0; j < FR; j++)
          acc[i][j] = __builtin_amdgcn_mfma_f32_16x16x32_bf16(af[i], bfv[j], acc[i][j], 0, 0, 0);
    }
    __syncthreads();

    bk += 64;
    if (kPerE > 0 && bk >= kPerE) { bk = 0; eOff += bExpStride; }
  }

  bf16*  Cb = (bf16*)Cv + (long)z * zC;
  float* Cf = (float*)Cv + (long)z * zC;
  const float* auxp = aux + (long)z * auxZ;
  const int mB = tileM + wr * (TILE / 2) + quad * 4;
  const int nB = tileN + wc * (TILE / 2) + r16;
#pragma unroll
  for (int i = 0; i < FR; i++) {
#pragma unroll
    for (int r = 0; r < 4; r++) {
      int gm = mB + i * 16 + r;
      if (gm >= M) continue;
      float rowAux = 0.f;
      if constexpr (EPI == EPI_SILU) rowAux = auxp[(long)gm * auxRS];
#pragma unroll
      for (int j = 0; j < FR; j++) {
        int gn = nB + j * 16;
        if (gn >= N) continue;
        float v = acc[i][j][r];
        long off = (long)gm * ldc + gn;
        if constexpr (EPI == EPI_BF16)      Cb[off] = (bf16)v;
        else if constexpr (EPI == EPI_F32)  Cf[off] = v;
        else if constexpr (EPI == EPI_ADD)  Cf[off] = auxp[(long)gm * auxRS + gn] + v;
        else if constexpr (EPI == EPI_SILU) { float sv = v / (1.f + __expf(-v)); Cb[off] = (bf16)(sv * rowAux); }
        else                                atomicAdd(&Cf[off], v);
      }
    }
  }
}

// ---------------------------------------------------------------------------
// Flash attention (causal): Q,K [NH][S][128], V^T [NH][64][S] -> ctx [S][NH*64]
// grid (NH, S/64); 4 waves, wave w owns q-rows qt*64+w*16..+15.
// ---------------------------------------------------------------------------
__global__ void __launch_bounds__(256) flash_k(
    const bf16* __restrict__ q, const bf16* __restrict__ k,
    const bf16* __restrict__ vt, bf16* __restrict__ ctx, float scale)
{
  const int h  = blockIdx.x;
  const int qt = (int)gridDim.y - 1 - (int)blockIdx.y;   // long blocks first
  const int tid = threadIdx.x, lane = tid & 63, wave = tid >> 6;
  const int quad = lane >> 4, r16 = lane & 15;

  __shared__ __align__(16) bf16 Ks[64 * 128];   // [key][d]  16-chunk swizzle
  __shared__ __align__(16) bf16 Vs[64 * 64];    // [d][key]   8-chunk swizzle
  __shared__ __align__(16) bf16 Ps[4][16 * 64]; // per-wave P, 8-chunk swizzle
  char* KsB = (char*)Ks;
  char* VsB = (char*)Vs;
  char* PsB = (char*)&Ps[wave][0];

  bf16x8 qf[4];
  {
    const bf16* qp = q + ((long)h * S_ + qt * 64 + wave * 16 + r16) * 128 + quad * 8;
#pragma unroll
    for (int ks = 0; ks < 4; ks++) qf[ks] = *(const bf16x8*)(qp + ks * 32);
  }

  const bf16* kG[4]; char* kL[4];
#pragma unroll
  for (int i = 0; i < 4; i++) {
    int n = (wave * 4 + i) * 64 + lane;
    int row = n >> 4, c = n & 15;
    kG[i] = k + ((long)h * S_ + row) * 128 + ((c ^ (row & 15)) << 3);
    kL[i] = KsB + (long)(wave * 4 + i) * 1024;
  }
  const bf16* vG[2]; char* vL[2];
#pragma unroll
  for (int i = 0; i < 2; i++) {
    int n = (wave * 2 + i) * 64 + lane;
    int row = n >> 3, c = n & 7;
    vG[i] = vt + ((long)h * 64 + row) * S_ + ((c ^ (row & 7)) << 3);
    vL[i] = VsB + (long)(wave * 2 + i) * 1024;
  }

  float mr[4], lr[4];
#pragma unroll
  for (int r = 0; r < 4; r++) { mr[r] = -1e30f; lr[r] = 0.f; }
  f32x4 o[4];
#pragma unroll
  for (int j = 0; j < 4; j++)
#pragma unroll
    for (int r = 0; r < 4; r++) o[j][r] = 0.f;

  for (int kt = 0; kt <= qt; kt++) {
#pragma unroll
    for (int i = 0; i < 4; i++) gload16(kG[i] + (long)kt * 64 * 128, kL[i]);
#pragma unroll
    for (int i = 0; i < 2; i++) gload16(vG[i] + kt * 64, vL[i]);
    __syncthreads();

    f32x4 s[4];
#pragma unroll
    for (int j = 0; j < 4; j++)
#pragma unroll
      for (int r = 0; r < 4; r++) s[j][r] = 0.f;
#pragma unroll
    for (int ks = 0; ks < 4; ks++) {
#pragma unroll
      for (int j = 0; j < 4; j++) {
        int row = j * 16 + r16;
        int c = ks * 4 + quad;
        bf16x8 bfr = *(const bf16x8*)(KsB + row * 256 + ((c ^ (row & 15)) << 4));
        s[j] = __builtin_amdgcn_mfma_f32_16x16x32_bf16(qf[ks], bfr, s[j], 0, 0, 0);
      }
    }

    if (kt == qt) {
#pragma unroll
      for (int j = 0; j < 4; j++)
#pragma unroll
        for (int r = 0; r < 4; r++)
          if (j * 16 + r16 > wave * 16 + quad * 4 + r) s[j][r] = -1e30f;
    }

    float pj[4][4];
#pragma unroll
    for (int r = 0; r < 4; r++) {
      float mx = fmaxf(fmaxf(s[0][r], s[1][r]), fmaxf(s[2][r], s[3][r]));
#pragma unroll
      for (int off = 1; off < 16; off <<= 1) mx = fmaxf(mx, __shfl_xor(mx, off, 64));
      mx *= scale;
      float nm = fmaxf(mr[r], mx);
      float alpha = __expf(mr[r] - nm);
      mr[r] = nm;
      float rs = 0.f;
#pragma unroll
      for (int j = 0; j < 4; j++) { float e = __expf(s[j][r] * scale - nm); pj[j][r] = e; rs += e; }
#pragma unroll
      for (int off = 1; off < 16; off <<= 1) rs += __shfl_xor(rs, off, 64);
      lr[r] = lr[r] * alpha + rs;
#pragma unroll
      for (int j = 0; j < 4; j++) o[j][r] *= alpha;
    }

#pragma unroll
    for (int j = 0; j < 4; j++) {
      int chunk = j * 2 + (r16 >> 3);
#pragma unroll
      for (int r = 0; r < 4; r++) {
        int row = quad * 4 + r;
        *(bf16*)(PsB + row * 128 + ((chunk ^ (row & 7)) << 4) + ((r16 & 7) << 1)) = (bf16)pj[j][r];
      }
    }

#pragma unroll
    for (int ks = 0; ks < 2; ks++) {
      int c = ks * 4 + quad;
      bf16x8 af = *(const bf16x8*)(PsB + r16 * 128 + ((c ^ (r16 & 7)) << 4));
#pragma unroll
      for (int j = 0; j < 4; j++) {
        int row = j * 16 + r16;
        bf16x8 bfr = *(const bf16x8*)(VsB + row * 128 + ((c ^ (row & 7)) << 4));
        o[j] = __builtin_amdgcn_mfma_f32_16x16x32_bf16(af, bfr, o[j], 0, 0, 0);
      }
    }
    __syncthreads();
  }

  bf16* cp = ctx + ((long)(qt * 64 + wave * 16 + quad * 4)) * (NH_ * 64) + h * 64 + r16;
#pragma unroll
  for (int r = 0; r < 4; r++) {
    float rl = 1.f / lr[r];
#pragma unroll
    for (int j = 0; j < 4; j++)
      cp[(long)r * NH_ * 64 + j * 16] = (bf16)(o[j][r] * rl);
  }
}

// ---------------------------------------------------------------------------
template <int NIT>
__global__ void __launch_bounds__(256) rmsnorm_k(
    const float* __restrict__ x, const float* __restrict__ w,
    bf16* __restrict__ out, int inStride)
{
  const int row = blockIdx.x, tid = threadIdx.x;
  const float* xr = x + (long)row * inStride;
  float vals[NIT];
  float ss = 0.f;
#pragma unroll
  for (int i = 0; i < NIT; i++) { float v = xr[i * 256 + tid]; vals[i] = v; ss += v * v; }
#pragma unroll
  for (int o = 32; o; o >>= 1) ss += __shfl_xor(ss, o, 64);
  __shared__ float red[4];
  if ((tid & 63) == 0) red[tid >> 6] = ss;
  __syncthreads();
  ss = red[0] + red[1] + red[2] + red[3];
  const float rinv = rsqrtf(ss / (float)(NIT * 256) + EPS_);
  bf16* orow = out + (long)row * (NIT * 256);
#pragma unroll
  for (int i = 0; i < NIT; i++) { int c = i * 256 + tid; orow[c] = (bf16)(w[c] * vals[i] * rinv); }
}

// ---------------------------------------------------------------------------
__global__ void prep_qkv_k(const bf16* __restrict__ q, const bf16* __restrict__ kv,
                           const float* __restrict__ ckv, const int* __restrict__ pos,
                           bf16* __restrict__ query, bf16* __restrict__ key,
                           bf16* __restrict__ vvT)
{
  const int s = blockIdx.x, h = blockIdx.y, d = threadIdx.x;
  const long qkOff = ((long)h * S_ + s) * QH_ + d;
  if (d < 64) {
    query[qkOff] = q[(long)s * H_ + h * QH_ + d];
    key[qkOff]   = kv[(long)s * H_ + h * QH_ + d];
    vvT[((long)h * 64 + d) * S_ + s] = kv[(long)s * H_ + h * QH_ + 64 + d];
  } else {
    const int i = d - 64;
    const float p = (float)pos[s];
    const float invf = powf(10000.f, -(float)(2 * (i & 31)) / 64.f);
    const float ang = p * invf;
    const float cc = cosf(ang), sn = sinf(ang);
    const float xq  = (float)q[(long)s * H_ + h * QH_ + 64 + i];
    const float xqr = (i < 32) ? -(float)q[(long)s * H_ + h * QH_ + 64 + i + 32]
                               :  (float)q[(long)s * H_ + h * QH_ + 64 + i - 32];
    query[qkOff] = (bf16)(xq * cc + xqr * sn);
    const float xk  = ckv[(long)s * 320 + 256 + i];
    const float xkr = (i < 32) ? -ckv[(long)s * 320 + 256 + i + 32]
                               :  ckv[(long)s * 320 + 256 + i - 32];
    key[qkOff] = (bf16)(xk * cc + xkr * sn);
  }
}

// ---------------------------------------------------------------------------
__global__ void __launch_bounds__(256) gate_k(const bf16* __restrict__ mlp,
                                              const float* __restrict__ gw,
                                              float* __restrict__ probs)
{
  const int s = blockIdx.x, tid = threadIdx.x;
  float acc[8];
#pragma unroll
  for (int e = 0; e < 8; e++) acc[e] = 0.f;
  for (int c = tid; c < H_; c += 256) {
    float x = (float)mlp[(long)s * H_ + c];
#pragma unroll
    for (int e = 0; e < 8; e++) acc[e] += x * gw[e * H_ + c];
  }
  __shared__ float red[4][8];
#pragma unroll
  for (int e = 0; e < 8; e++) {
    float v = acc[e];
#pragma unroll
    for (int o = 32; o; o >>= 1) v += __shfl_xor(v, o, 64);
    if ((tid & 63) == 0) red[tid >> 6][e] = v;
  }
  __syncthreads();
  if (tid == 0) {
    float l[8]; float mx = -1e30f;
#pragma unroll
    for (int e = 0; e < 8; e++) { l[e] = red[0][e] + red[1][e] + red[2][e] + red[3][e]; mx = fmaxf(mx, l[e]); }
    float sum = 0.f;
#pragma unroll
    for (int e = 0; e < 8; e++) { l[e] = __expf(l[e] - mx); sum += l[e]; }
    float r = 1.f / sum;
#pragma unroll
    for (int e = 0; e < 8; e++) probs[(long)s * 8 + e] = l[e] * r;
  }
}

// ---------------------------------------------------------------------------
__global__ void __launch_bounds__(256) wconv_k(const float* __restrict__ in,
                                               bf16* __restrict__ out, int n8)
{
  int i = blockIdx.x * 256 + threadIdx.x;
  if (i < n8) {
    f32x4 a = ((const f32x4*)in)[2 * i];
    f32x4 b = ((const f32x4*)in)[2 * i + 1];
    bf16x8 v;
    v[0] = (bf16)a[0]; v[1] = (bf16)a[1]; v[2] = (bf16)a[2]; v[3] = (bf16)a[3];
    v[4] = (bf16)b[0]; v[5] = (bf16)b[1]; v[6] = (bf16)b[2]; v[7] = (bf16)b[3];
    ((bf16x8*)out)[i] = v;
  }
}

// ---------------------------------------------------------------------------
extern "C" void kernel_launch(void* const* d_in, const int* in_sizes, int n_in,
                              void* d_out, int out_size, void* d_ws, size_t ws_size,
                              hipStream_t stream)
{
  const int*   positions = (const int*)  d_in[0];
  const float* hidden    = (const float*)d_in[1];
  const float* ln1       = (const float*)d_in[2];
  const float* wq        = (const float*)d_in[3];
  const float* wkva      = (const float*)d_in[4];
  const float* lnkv      = (const float*)d_in[5];
  const float* wkvb      = (const float*)d_in[6];
  const float* wo        = (const float*)d_in[7];
  const float* ln2       = (const float*)d_in[8];
  const float* wg        = (const float*)d_in[9];
  const float* wfc1      = (const float*)d_in[10];
  const float* wfc2      = (const float*)d_in[11];
  float* out = (float*)d_out;

  char* wsb = (char*)d_ws;
  size_t off = 0;
  auto alloc = [&](size_t bytes) -> void* {
    void* p = wsb + off;
    off += (bytes + 255) & ~(size_t)255;
    return p;
  };
  bf16*  sa_in = (bf16*) alloc((size_t)S_ * H_ * 2);
  bf16*  qb    = (bf16*) alloc((size_t)S_ * H_ * 2);
  float* ckv   = (float*)alloc((size_t)S_ * 320 * 4);
  bf16*  ckvn  = (bf16*) alloc((size_t)S_ * KV_RANK_ * 2);
  bf16*  kvb   = (bf16*) alloc((size_t)S_ * H_ * 2);
  bf16*  query = (bf16*) alloc((size_t)NH_ * S_ * QH_ * 2);
  bf16*  key   = (bf16*) alloc((size_t)NH_ * S_ * QH_ * 2);
  bf16*  vvT   = (bf16*) alloc((size_t)NH_ * 64 * S_ * 2);
  bf16*  ctx   = (bf16*) alloc((size_t)S_ * NH_ * 64 * 2);
  bf16*  mlp   = (bf16*) alloc((size_t)S_ * H_ * 2);
  float* probs = (float*)alloc((size_t)S_ * 8 * 4);
  bf16*  hbuf  = (bf16*) alloc((size_t)S_ * EXP_ * INTER_ * 2);

  const size_t MBy = (size_t)1 << 20;
  const size_t rem = (ws_size > off) ? ws_size - off : 0;
  const size_t szMoeW = (size_t)EXP_ * INTER_ * H_ * 2;      // 46.1 MB each
  const bool cw = (rem >= 93 * MBy);

  bf16* fc1b = nullptr; bf16* fc2b = nullptr;
  if (cw) { fc1b = (bf16*)alloc(szMoeW); fc2b = (bf16*)alloc(szMoeW); }
  // attention weights (bf16) alias hbuf (dead until fc1; o_proj finishes first)
  bf16* wqb   = (bf16*)hbuf;
  bf16* wkvab = wqb   + (size_t)H_ * H_;
  bf16* wkvbb = wkvab + (size_t)320 * H_;
  bf16* wob   = wkvbb + (size_t)H_ * KV_RANK_;

  const float scale = 0.08838834764831845f;   // 128^-0.5

  rmsnorm_k<8><<<S_, 256, 0, stream>>>(hidden, ln1, sa_in, H_);

  if (cw) {
    wconv_k<<<(H_*H_/8 + 255)/256, 256, 0, stream>>>(wq, wqb, H_*H_/8);
    wconv_k<<<(320*H_/8 + 255)/256, 256, 0, stream>>>(wkva, wkvab, 320*H_/8);
    wconv_k<<<(H_*KV_RANK_/8 + 255)/256, 256, 0, stream>>>(wkvb, wkvbb, H_*KV_RANK_/8);
    wconv_k<<<(H_*NH_*64/8 + 255)/256, 256, 0, stream>>>(wo, wob, H_*NH_*64/8);
    wconv_k<<<(EXP_*INTER_*H_/8 + 255)/256, 256, 0, stream>>>(wfc1, fc1b, EXP_*INTER_*H_/8);
    wconv_k<<<(EXP_*INTER_*H_/8 + 255)/256, 256, 0, stream>>>(wfc2, fc2b, EXP_*INTER_*H_/8);
  }

  // q_proj [2048x2048, K=2048]
  if (cw) gemm_bt<EPI_BF16, bf16, 64><<<dim3(32,32,1), 256, 0, stream>>>(
      sa_in, wqb, qb, hidden, S_, H_, H_, H_, H_, H_, 0,0,0,0,0, 0,0,0);
  else    gemm_bt<EPI_BF16, float, 64><<<dim3(32,32,1), 256, 0, stream>>>(
      sa_in, wq,  qb, hidden, S_, H_, H_, H_, H_, H_, 0,0,0,0,0, 0,0,0);

  // kv_a [2048x320, K=2048] -> fp32
  if (cw) gemm_bt<EPI_F32, bf16, 64><<<dim3(5,32,1), 256, 0, stream>>>(
      sa_in, wkvab, ckv, hidden, S_, 320, H_, H_, H_, 320, 0,0,0,0,0, 0,0,0);
  else    gemm_bt<EPI_F32, float, 64><<<dim3(5,32,1), 256, 0, stream>>>(
      sa_in, wkva,  ckv, hidden, S_, 320, H_, H_, H_, 320, 0,0,0,0,0, 0,0,0);

  rmsnorm_k<1><<<S_, 256, 0, stream>>>(ckv, lnkv, ckvn, 320);

  // kv_b [2048x2048, K=256]
  if (cw) gemm_bt<EPI_BF16, bf16, 64><<<dim3(32,32,1), 256, 0, stream>>>(
      ckvn, wkvbb, kvb, hidden, S_, H_, KV_RANK_, KV_RANK_, KV_RANK_, H_, 0,0,0,0,0, 0,0,0);
  else    gemm_bt<EPI_BF16, float, 64><<<dim3(32,32,1), 256, 0, stream>>>(
      ckvn, wkvb,  kvb, hidden, S_, H_, KV_RANK_, KV_RANK_, KV_RANK_, H_, 0,0,0,0,0, 0,0,0);

  prep_qkv_k<<<dim3(S_, NH_), 128, 0, stream>>>(qb, kvb, ckv, positions, query, key, vvT);

  // fused causal attention -> ctx
  flash_k<<<dim3(NH_, S_/64), 256, 0, stream>>>(query, key, vvT, ctx, scale);

  // o_proj: out = hidden + ctx @ wo^T   (writes d_out directly)
  if (cw) gemm_bt<EPI_ADD, bf16, 64><<<dim3(32,32,1), 256, 0, stream>>>(
      ctx, wob, out, hidden, S_, H_, NH_*64, NH_*64, NH_*64, H_, 0,0,0,0, H_, 0,0,0);
  else    gemm_bt<EPI_ADD, float, 64><<<dim3(32,32,1), 256, 0, stream>>>(
      ctx, wo,  out, hidden, S_, H_, NH_*64, NH_*64, NH_*64, H_, 0,0,0,0, H_, 0,0,0);

  rmsnorm_k<8><<<S_, 256, 0, stream>>>(out, ln2, mlp, H_);
  gate_k<<<S_, 256, 0, stream>>>(mlp, wg, probs);

  // fc1: hbuf[s][e*1408+i] = silu(mlp @ fc1_w[e]^T) * probs[s][e]
  // XSWZ=1: 1408 wgs -> 176/XCD = exactly one expert per XCD (B panel 5.8MB
  // vs per-XCD 4MB L2 + L3 backstop, vs 8-expert interleave before).
  if (cw) gemm_bt<EPI_SILU, bf16, 128, 1><<<dim3(11,16,8), 256, 0, stream>>>(
      mlp, fc1b, hbuf, probs, S_, INTER_, H_, H_, H_, EXP_*INTER_,
      0, (long)INTER_*H_, INTER_, 1, 8, 0, 0, 0);
  else    gemm_bt<EPI_SILU, float, 128, 1><<<dim3(11,16,8), 256, 0, stream>>>(
      mlp, wfc1, hbuf, probs, S_, INTER_, H_, H_, H_, EXP_*INTER_,
      0, (long)INTER_*H_, INTER_, 1, 8, 0, 0, 0);

  // fc2: z=4, each z covers 2 experts flat-K (K=2816, kPerE hop), atomicAdd
  // fp32 into out. XSWZ=1: 1024 wgs -> 128/XCD contiguous chunk.
  if (cw) gemm_bt<EPI_ATOM, bf16, 128, 1><<<dim3(16,16,4), 256, 0, stream>>>(
      hbuf, fc2b, out, hidden, S_, H_, 2*INTER_, EXP_*INTER_, 0, H_,
      (long)(2*INTER_), 0, 0, 0, 0, INTER_, (long)H_*INTER_, 2);
  else    gemm_bt<EPI_ATOM, float, 128, 1><<<dim3(16,16,4), 256, 0, stream>>>(
      hbuf, wfc2, out, hidden, S_, H_, 2*INTER_, EXP_*INTER_, 0, H_,
      (long)(2*INTER_), 0, 0, 0, 0, INTER_, (long)H_*INTER_, 2);
}

// Round 5
// 652.703 us; speedup vs baseline: 1.3828x; 1.0521x over previous
//
#include <hip/hip_runtime.h>
#include <cstdint>
#include <cstddef>

typedef __bf16 bf16;
typedef __bf16 bf16x8 __attribute__((ext_vector_type(8)));
typedef float  f32x4  __attribute__((ext_vector_type(4)));

constexpr int S_      = 2048;
constexpr int H_      = 2048;
constexpr int NH_     = 16;
constexpr int KV_RANK_= 256;
constexpr int EXP_    = 8;
constexpr int INTER_  = 1408;
constexpr int QH_     = 128;
constexpr float EPS_  = 1e-6f;

__device__ inline void gload16(const void* g, void* l) {
  __builtin_amdgcn_global_load_lds(
      (const __attribute__((address_space(1))) void*)g,
      (__attribute__((address_space(3))) void*)l, 16, 0, 0);
}

enum { EPI_BF16 = 0, EPI_F32 = 1, EPI_ADD = 2, EPI_SILU = 3, EPI_ATOM = 4 };

// ---------------------------------------------------------------------------
// MFMA GEMM: C[M,N] (+)= A[M,K] @ B[N,K]^T   (BK=64, TILE in {64,128})
//  4 waves as 2x2, each wave (TILE/2)^2 via FRxFRx2 mfma_f32_16x16x32_bf16.
//  XOR-swizzled LDS (conflict-free), staging via global_load_lds width=16.
//  kPerE>0: flat-K MoE, B base hops every kPerE cols by bExpStride.
//  launch_bounds(256,3): 60 VGPR + 64 AGPR fits 4 waves/EU; declaring 5
//  squeezed the allocator to 48 VGPR and cost 75% on fc1 (round-3 lesson).
//  XSWZ=1: XCD-chunked bijective remap (requires nwg%8==0); proven win on
//  fc1/fc2 (round-4: fc2 FETCH 283->106MB, -20us). Not applied to L2-fit
//  attention GEMMs (guide: neutral-to-negative when L3-fit).
// ---------------------------------------------------------------------------
template <int EPI, typename TB, int TILE, int XSWZ = 0>
__global__ void __launch_bounds__(256, 3) gemm_bt(
    const bf16* __restrict__ A, const TB* __restrict__ B,
    void* __restrict__ Cv, const float* __restrict__ aux,
    int M, int N, int K, int lda, int ldb, int ldc,
    long zA, long zB, long zC, long auxZ, int auxRS,
    int kPerE, long bExpStride, int expBasePerZ)
{
  constexpr int FR = TILE / 32;
  int bx = blockIdx.x, by = blockIdx.y, bz = blockIdx.z;
  if constexpr (XSWZ) {
    const int gx = (int)gridDim.x, gy = (int)gridDim.y;
    const int nwg = gx * gy * (int)gridDim.z;
    int lin = (bz * gy + by) * gx + bx;
    const int cpx = nwg >> 3;
    int w = (lin & 7) * cpx + (lin >> 3);
    bx = w % gx; w /= gx;
    by = w % gy; bz = w / gy;
  }
  const int tileN = bx * TILE;
  const int tileM = by * TILE;
  const int z = bz;
  A += (long)z * zA;

  __shared__ __align__(16) bf16 As[TILE * 64];
  __shared__ __align__(16) TB   Bs[TILE * 64];
  char* AsB = (char*)As;
  char* BsB = (char*)Bs;

  const int tid  = threadIdx.x;
  const int lane = tid & 63;
  const int wave = tid >> 6;
  const int wr = wave >> 1, wc = wave & 1;
  const int quad = lane >> 4, r16 = lane & 15;

  const int ldbe = (kPerE > 0) ? kPerE : ldb;
  const TB* BzBase = (kPerE > 0) ? (B + (long)z * expBasePerZ * bExpStride)
                                 : (B + (long)z * zB);

  constexpr int IA = TILE / 32;
  const bf16* aG[IA]; char* aL[IA];
#pragma unroll
  for (int i = 0; i < IA; i++) {
    int n = (wave * IA + i) * 64 + lane;
    int row = n >> 3, cp = n & 7;
    int cc = (cp ^ (row & 7)) << 3;
    int rowg = tileM + row; if (rowg > M - 1) rowg = M - 1;
    aG[i] = A + (long)rowg * lda + cc;
    aL[i] = AsB + (long)(wave * IA + i) * 1024;
  }
  constexpr int IB = (sizeof(TB) == 4) ? (TILE / 16) : (TILE / 32);
  const TB* bG[IB]; char* bL[IB];
#pragma unroll
  for (int i = 0; i < IB; i++) {
    int n = (wave * IB + i) * 64 + lane;
    int row, cc;
    if constexpr (sizeof(TB) == 4) { row = n >> 4; cc = ((n & 15) ^ (row & 15)) << 2; }
    else                           { row = n >> 3; cc = ((n & 7)  ^ (row & 7))  << 3; }
    int rowg = tileN + row; if (rowg > N - 1) rowg = N - 1;
    bG[i] = BzBase + (long)rowg * ldbe + cc;
    bL[i] = BsB + (long)(wave * IB + i) * 1024;
  }

  int aOff[FR], bOff[FR];
#pragma unroll
  for (int i = 0; i < FR; i++) {
    int row = wr * (TILE / 2) + i * 16 + r16;
    aOff[i] = row * 128 + ((quad ^ (row & 7)) << 4);
  }
#pragma unroll
  for (int j = 0; j < FR; j++) {
    int row = wc * (TILE / 2) + j * 16 + r16;
    if constexpr (sizeof(TB) == 4) bOff[j] = row * 256 + (((2 * quad) ^ (row & 15)) << 4);
    else                           bOff[j] = row * 128 + ((quad ^ (row & 7)) << 4);
  }

  f32x4 acc[FR][FR];
#pragma unroll
  for (int i = 0; i < FR; i++)
#pragma unroll
    for (int j = 0; j < FR; j++)
#pragma unroll
      for (int r = 0; r < 4; r++) acc[i][j][r] = 0.f;

  int bk = 0; long eOff = 0;
  for (int k0 = 0; k0 < K; k0 += 64) {
#pragma unroll
    for (int i = 0; i < IA; i++) gload16(aG[i] + k0, aL[i]);
#pragma unroll
    for (int i = 0; i < IB; i++) gload16(bG[i] + eOff + bk, bL[i]);
    __syncthreads();

#pragma unroll
    for (int s = 0; s < 2; s++) {
      bf16x8 af[FR], bfv[FR];
#pragma unroll
      for (int i = 0; i < FR; i++)
        af[i] = *(const bf16x8*)(AsB + (aOff[i] ^ (s << 6)));
#pragma unroll
      for (int j = 0; j < FR; j++) {
        if constexpr (sizeof(TB) == 2) {
          bfv[j] = *(const bf16x8*)(BsB + (bOff[j] ^ (s << 6)));
        } else {
          int a0 = bOff[j] ^ (s << 7);
          f32x4 lo = *(const f32x4*)(BsB + a0);
          f32x4 hi = *(const f32x4*)(BsB + (a0 ^ 16));
          bf16x8 v;
          v[0]=(bf16)lo[0]; v[1]=(bf16)lo[1]; v[2]=(bf16)lo[2]; v[3]=(bf16)lo[3];
          v[4]=(bf16)hi[0]; v[5]=(bf16)hi[1]; v[6]=(bf16)hi[2]; v[7]=(bf16)hi[3];
          bfv[j] = v;
        }
      }
#pragma unroll
      for (int i = 0; i < FR; i++)
#pragma unroll
        for (int j = 0; j < FR; j++)
          acc[i][j] = __builtin_amdgcn_mfma_f32_16x16x32_bf16(af[i], bfv[j], acc[i][j], 0, 0, 0);
    }
    __syncthreads();

    bk += 64;
    if (kPerE > 0 && bk >= kPerE) { bk = 0; eOff += bExpStride; }
  }

  bf16*  Cb = (bf16*)Cv + (long)z * zC;
  float* Cf = (float*)Cv + (long)z * zC;
  const float* auxp = aux + (long)z * auxZ;
  const int mB = tileM + wr * (TILE / 2) + quad * 4;
  const int nB = tileN + wc * (TILE / 2) + r16;
#pragma unroll
  for (int i = 0; i < FR; i++) {
#pragma unroll
    for (int r = 0; r < 4; r++) {
      int gm = mB + i * 16 + r;
      if (gm >= M) continue;
      float rowAux = 0.f;
      if constexpr (EPI == EPI_SILU) rowAux = auxp[(long)gm * auxRS];
#pragma unroll
      for (int j = 0; j < FR; j++) {
        int gn = nB + j * 16;
        if (gn >= N) continue;
        float v = acc[i][j][r];
        long off = (long)gm * ldc + gn;
        if constexpr (EPI == EPI_BF16)      Cb[off] = (bf16)v;
        else if constexpr (EPI == EPI_F32)  Cf[off] = v;
        else if constexpr (EPI == EPI_ADD)  Cf[off] = auxp[(long)gm * auxRS + gn] + v;
        else if constexpr (EPI == EPI_SILU) { float sv = v / (1.f + __expf(-v)); Cb[off] = (bf16)(sv * rowAux); }
        else                                atomicAdd(&Cf[off], v);
      }
    }
  }
}

// ---------------------------------------------------------------------------
// Merged q_proj + kv_a GEMM (bf16 weights, TILE=64 structure of gemm_bt).
// grid (37, 32): bx<32 -> q tile (C=qb bf16, N=2048); bx>=32 -> kv_a tile
// (C=ckv fp32, N=320). Same A (sa_in), same K=2048, same ldb=2048.
// All tile bounds exact multiples of 64 -> no clamps needed.
// ---------------------------------------------------------------------------
__global__ void __launch_bounds__(256, 3) gemm_qkva(
    const bf16* __restrict__ A, const bf16* __restrict__ Bq,
    const bf16* __restrict__ Bkva, bf16* __restrict__ Cq,
    float* __restrict__ Ckva)
{
  constexpr int TILE = 64, FR = 2, IA = 2, IB = 2;
  const bool kva = ((int)blockIdx.x >= 32);
  const int tileN = (kva ? ((int)blockIdx.x - 32) : (int)blockIdx.x) * TILE;
  const int tileM = blockIdx.y * TILE;
  const bf16* B = kva ? Bkva : Bq;

  __shared__ __align__(16) bf16 As[TILE * 64];
  __shared__ __align__(16) bf16 Bs[TILE * 64];
  char* AsB = (char*)As;
  char* BsB = (char*)Bs;

  const int tid  = threadIdx.x;
  const int lane = tid & 63;
  const int wave = tid >> 6;
  const int wr = wave >> 1, wc = wave & 1;
  const int quad = lane >> 4, r16 = lane & 15;

  const bf16* aG[IA]; char* aL[IA];
  const bf16* bG[IB]; char* bL[IB];
#pragma unroll
  for (int i = 0; i < IA; i++) {
    int n = (wave * IA + i) * 64 + lane;
    int row = n >> 3, cp = n & 7;
    int cc = (cp ^ (row & 7)) << 3;
    aG[i] = A + (long)(tileM + row) * H_ + cc;
    aL[i] = AsB + (long)(wave * IA + i) * 1024;
    bG[i] = B + (long)(tileN + row) * H_ + cc;
    bL[i] = BsB + (long)(wave * IB + i) * 1024;
  }

  int aOff[FR], bOff[FR];
#pragma unroll
  for (int i = 0; i < FR; i++) {
    int row = wr * 32 + i * 16 + r16;
    aOff[i] = row * 128 + ((quad ^ (row & 7)) << 4);
  }
#pragma unroll
  for (int j = 0; j < FR; j++) {
    int row = wc * 32 + j * 16 + r16;
    bOff[j] = row * 128 + ((quad ^ (row & 7)) << 4);
  }

  f32x4 acc[FR][FR];
#pragma unroll
  for (int i = 0; i < FR; i++)
#pragma unroll
    for (int j = 0; j < FR; j++)
#pragma unroll
      for (int r = 0; r < 4; r++) acc[i][j][r] = 0.f;

  for (int k0 = 0; k0 < H_; k0 += 64) {
#pragma unroll
    for (int i = 0; i < IA; i++) gload16(aG[i] + k0, aL[i]);
#pragma unroll
    for (int i = 0; i < IB; i++) gload16(bG[i] + k0, bL[i]);
    __syncthreads();

#pragma unroll
    for (int s = 0; s < 2; s++) {
      bf16x8 af[FR], bfv[FR];
#pragma unroll
      for (int i = 0; i < FR; i++)
        af[i] = *(const bf16x8*)(AsB + (aOff[i] ^ (s << 6)));
#pragma unroll
      for (int j = 0; j < FR; j++)
        bfv[j] = *(const bf16x8*)(BsB + (bOff[j] ^ (s << 6)));
#pragma unroll
      for (int i = 0; i < FR; i++)
#pragma unroll
        for (int j = 0; j < FR; j++)
          acc[i][j] = __builtin_amdgcn_mfma_f32_16x16x32_bf16(af[i], bfv[j], acc[i][j], 0, 0, 0);
    }
    __syncthreads();
  }

  const int mB = tileM + wr * 32 + quad * 4;
  const int nB = tileN + wc * 32 + r16;
#pragma unroll
  for (int i = 0; i < FR; i++) {
#pragma unroll
    for (int r = 0; r < 4; r++) {
      const int gm = mB + i * 16 + r;
#pragma unroll
      for (int j = 0; j < FR; j++) {
        const int gn = nB + j * 16;
        float v = acc[i][j][r];
        if (kva) Ckva[(long)gm * 320 + gn] = v;
        else     Cq[(long)gm * H_ + gn]    = (bf16)v;
      }
    }
  }
}

// ---------------------------------------------------------------------------
// Flash attention (causal): Q,K [NH][S][128], V^T [NH][64][S] -> ctx [S][NH*64]
// grid (NH, S/64); 4 waves, wave w owns q-rows qt*64+w*16..+15.
// ---------------------------------------------------------------------------
__global__ void __launch_bounds__(256) flash_k(
    const bf16* __restrict__ q, const bf16* __restrict__ k,
    const bf16* __restrict__ vt, bf16* __restrict__ ctx, float scale)
{
  const int h  = blockIdx.x;
  const int qt = (int)gridDim.y - 1 - (int)blockIdx.y;   // long blocks first
  const int tid = threadIdx.x, lane = tid & 63, wave = tid >> 6;
  const int quad = lane >> 4, r16 = lane & 15;

  __shared__ __align__(16) bf16 Ks[64 * 128];   // [key][d]  16-chunk swizzle
  __shared__ __align__(16) bf16 Vs[64 * 64];    // [d][key]   8-chunk swizzle
  __shared__ __align__(16) bf16 Ps[4][16 * 64]; // per-wave P, 8-chunk swizzle
  char* KsB = (char*)Ks;
  char* VsB = (char*)Vs;
  char* PsB = (char*)&Ps[wave][0];

  bf16x8 qf[4];
  {
    const bf16* qp = q + ((long)h * S_ + qt * 64 + wave * 16 + r16) * 128 + quad * 8;
#pragma unroll
    for (int ks = 0; ks < 4; ks++) qf[ks] = *(const bf16x8*)(qp + ks * 32);
  }

  const bf16* kG[4]; char* kL[4];
#pragma unroll
  for (int i = 0; i < 4; i++) {
    int n = (wave * 4 + i) * 64 + lane;
    int row = n >> 4, c = n & 15;
    kG[i] = k + ((long)h * S_ + row) * 128 + ((c ^ (row & 15)) << 3);
    kL[i] = KsB + (long)(wave * 4 + i) * 1024;
  }
  const bf16* vG[2]; char* vL[2];
#pragma unroll
  for (int i = 0; i < 2; i++) {
    int n = (wave * 2 + i) * 64 + lane;
    int row = n >> 3, c = n & 7;
    vG[i] = vt + ((long)h * 64 + row) * S_ + ((c ^ (row & 7)) << 3);
    vL[i] = VsB + (long)(wave * 2 + i) * 1024;
  }

  float mr[4], lr[4];
#pragma unroll
  for (int r = 0; r < 4; r++) { mr[r] = -1e30f; lr[r] = 0.f; }
  f32x4 o[4];
#pragma unroll
  for (int j = 0; j < 4; j++)
#pragma unroll
    for (int r = 0; r < 4; r++) o[j][r] = 0.f;

  for (int kt = 0; kt <= qt; kt++) {
#pragma unroll
    for (int i = 0; i < 4; i++) gload16(kG[i] + (long)kt * 64 * 128, kL[i]);
#pragma unroll
    for (int i = 0; i < 2; i++) gload16(vG[i] + kt * 64, vL[i]);
    __syncthreads();

    f32x4 s[4];
#pragma unroll
    for (int j = 0; j < 4; j++)
#pragma unroll
      for (int r = 0; r < 4; r++) s[j][r] = 0.f;
#pragma unroll
    for (int ks = 0; ks < 4; ks++) {
#pragma unroll
      for (int j = 0; j < 4; j++) {
        int row = j * 16 + r16;
        int c = ks * 4 + quad;
        bf16x8 bfr = *(const bf16x8*)(KsB + row * 256 + ((c ^ (row & 15)) << 4));
        s[j] = __builtin_amdgcn_mfma_f32_16x16x32_bf16(qf[ks], bfr, s[j], 0, 0, 0);
      }
    }

    if (kt == qt) {
#pragma unroll
      for (int j = 0; j < 4; j++)
#pragma unroll
        for (int r = 0; r < 4; r++)
          if (j * 16 + r16 > wave * 16 + quad * 4 + r) s[j][r] = -1e30f;
    }

    float pj[4][4];
#pragma unroll
    for (int r = 0; r < 4; r++) {
      float mx = fmaxf(fmaxf(s[0][r], s[1][r]), fmaxf(s[2][r], s[3][r]));
#pragma unroll
      for (int off = 1; off < 16; off <<= 1) mx = fmaxf(mx, __shfl_xor(mx, off, 64));
      mx *= scale;
      float nm = fmaxf(mr[r], mx);
      float alpha = __expf(mr[r] - nm);
      mr[r] = nm;
      float rs = 0.f;
#pragma unroll
      for (int j = 0; j < 4; j++) { float e = __expf(s[j][r] * scale - nm); pj[j][r] = e; rs += e; }
#pragma unroll
      for (int off = 1; off < 16; off <<= 1) rs += __shfl_xor(rs, off, 64);
      lr[r] = lr[r] * alpha + rs;
#pragma unroll
      for (int j = 0; j < 4; j++) o[j][r] *= alpha;
    }

#pragma unroll
    for (int j = 0; j < 4; j++) {
      int chunk = j * 2 + (r16 >> 3);
#pragma unroll
      for (int r = 0; r < 4; r++) {
        int row = quad * 4 + r;
        *(bf16*)(PsB + row * 128 + ((chunk ^ (row & 7)) << 4) + ((r16 & 7) << 1)) = (bf16)pj[j][r];
      }
    }

#pragma unroll
    for (int ks = 0; ks < 2; ks++) {
      int c = ks * 4 + quad;
      bf16x8 af = *(const bf16x8*)(PsB + r16 * 128 + ((c ^ (r16 & 7)) << 4));
#pragma unroll
      for (int j = 0; j < 4; j++) {
        int row = j * 16 + r16;
        bf16x8 bfr = *(const bf16x8*)(VsB + row * 128 + ((c ^ (row & 7)) << 4));
        o[j] = __builtin_amdgcn_mfma_f32_16x16x32_bf16(af, bfr, o[j], 0, 0, 0);
      }
    }
    __syncthreads();
  }

  bf16* cp = ctx + ((long)(qt * 64 + wave * 16 + quad * 4)) * (NH_ * 64) + h * 64 + r16;
#pragma unroll
  for (int r = 0; r < 4; r++) {
    float rl = 1.f / lr[r];
#pragma unroll
    for (int j = 0; j < 4; j++)
      cp[(long)r * NH_ * 64 + j * 16] = (bf16)(o[j][r] * rl);
  }
}

// ---------------------------------------------------------------------------
template <int NIT>
__global__ void __launch_bounds__(256) rmsnorm_k(
    const float* __restrict__ x, const float* __restrict__ w,
    bf16* __restrict__ out, int inStride)
{
  const int row = blockIdx.x, tid = threadIdx.x;
  const float* xr = x + (long)row * inStride;
  float vals[NIT];
  float ss = 0.f;
#pragma unroll
  for (int i = 0; i < NIT; i++) { float v = xr[i * 256 + tid]; vals[i] = v; ss += v * v; }
#pragma unroll
  for (int o = 32; o; o >>= 1) ss += __shfl_xor(ss, o, 64);
  __shared__ float red[4];
  if ((tid & 63) == 0) red[tid >> 6] = ss;
  __syncthreads();
  ss = red[0] + red[1] + red[2] + red[3];
  const float rinv = rsqrtf(ss / (float)(NIT * 256) + EPS_);
  bf16* orow = out + (long)row * (NIT * 256);
#pragma unroll
  for (int i = 0; i < NIT; i++) { int c = i * 256 + tid; orow[c] = (bf16)(w[c] * vals[i] * rinv); }
}

// ---------------------------------------------------------------------------
// Fused post-attention RMSNorm + MoE gate: writes bf16 mlp row AND probs[s][8]
// (normalized values feed the 8-expert dot from registers; saves the gate
// kernel's full re-read of mlp and one dispatch).
// ---------------------------------------------------------------------------
__global__ void __launch_bounds__(256) rmsgate_k(
    const float* __restrict__ x, const float* __restrict__ w,
    const float* __restrict__ gw, bf16* __restrict__ out,
    float* __restrict__ probs)
{
  const int row = blockIdx.x, tid = threadIdx.x;
  const float* xr = x + (long)row * H_;
  float vals[8];
  float ss = 0.f;
#pragma unroll
  for (int i = 0; i < 8; i++) { float v = xr[i * 256 + tid]; vals[i] = v; ss += v * v; }
#pragma unroll
  for (int o = 32; o; o >>= 1) ss += __shfl_xor(ss, o, 64);
  __shared__ float red[4];
  if ((tid & 63) == 0) red[tid >> 6] = ss;
  __syncthreads();
  ss = red[0] + red[1] + red[2] + red[3];
  const float rinv = rsqrtf(ss / 2048.f + EPS_);

  bf16* orow = out + (long)row * H_;
  float ga[8];
#pragma unroll
  for (int e = 0; e < 8; e++) ga[e] = 0.f;
#pragma unroll
  for (int i = 0; i < 8; i++) {
    int c = i * 256 + tid;
    float nv = w[c] * vals[i] * rinv;
    orow[c] = (bf16)nv;
#pragma unroll
    for (int e = 0; e < 8; e++) ga[e] += nv * gw[e * H_ + c];
  }
  __shared__ float redg[4][8];
#pragma unroll
  for (int e = 0; e < 8; e++) {
    float v = ga[e];
#pragma unroll
    for (int o = 32; o; o >>= 1) v += __shfl_xor(v, o, 64);
    if ((tid & 63) == 0) redg[tid >> 6][e] = v;
  }
  __syncthreads();
  if (tid == 0) {
    float l[8]; float mx = -1e30f;
#pragma unroll
    for (int e = 0; e < 8; e++) { l[e] = redg[0][e] + redg[1][e] + redg[2][e] + redg[3][e]; mx = fmaxf(mx, l[e]); }
    float sum = 0.f;
#pragma unroll
    for (int e = 0; e < 8; e++) { l[e] = __expf(l[e] - mx); sum += l[e]; }
    float r = 1.f / sum;
#pragma unroll
    for (int e = 0; e < 8; e++) probs[(long)row * 8 + e] = l[e] * r;
  }
}

// ---------------------------------------------------------------------------
// prep v2: one block per position s (2048 blocks). RoPE cos/sin computed ONCE
// per s into LDS (was per-head: 16x redundant powf+sincos), then 256 threads
// cover all 16 heads x 128 dims.
// ---------------------------------------------------------------------------
__global__ void __launch_bounds__(256) prep2_k(
    const bf16* __restrict__ q, const bf16* __restrict__ kv,
    const float* __restrict__ ckv, const int* __restrict__ pos,
    bf16* __restrict__ query, bf16* __restrict__ key,
    bf16* __restrict__ vvT)
{
  const int s = blockIdx.x, tid = threadIdx.x;
  __shared__ float cs[64], sn[64];
  if (tid < 64) {
    const int i = tid;
    const float invf = powf(10000.f, -(float)(2 * (i & 31)) / 64.f);
    const float ang = (float)pos[s] * invf;
    cs[i] = cosf(ang); sn[i] = sinf(ang);
  }
  __syncthreads();
#pragma unroll
  for (int it = 0; it < 8; ++it) {
    const int idx = it * 256 + tid;
    const int h = idx >> 7, d = idx & 127;
    const long qkOff = ((long)h * S_ + s) * QH_ + d;
    if (d < 64) {
      query[qkOff] = q[(long)s * H_ + h * QH_ + d];
      key[qkOff]   = kv[(long)s * H_ + h * QH_ + d];
      vvT[((long)h * 64 + d) * S_ + s] = kv[(long)s * H_ + h * QH_ + 64 + d];
    } else {
      const int i = d - 64;
      const float cc = cs[i], sv = sn[i];
      const float xq  = (float)q[(long)s * H_ + h * QH_ + 64 + i];
      const float xqr = (i < 32) ? -(float)q[(long)s * H_ + h * QH_ + 64 + i + 32]
                                 :  (float)q[(long)s * H_ + h * QH_ + 64 + i - 32];
      query[qkOff] = (bf16)(xq * cc + xqr * sv);
      const float xk  = ckv[(long)s * 320 + 256 + i];
      const float xkr = (i < 32) ? -ckv[(long)s * 320 + 256 + i + 32]
                                 :  ckv[(long)s * 320 + 256 + i - 32];
      key[qkOff] = (bf16)(xk * cc + xkr * sv);
    }
  }
}

// ---------------------------------------------------------------------------
// single-dispatch fp32->bf16 conversion of all six weight tensors
// ---------------------------------------------------------------------------
__device__ inline void cvt8(const float* __restrict__ in,
                            bf16* __restrict__ out, int i) {
  f32x4 a = ((const f32x4*)in)[2 * i];
  f32x4 b = ((const f32x4*)in)[2 * i + 1];
  bf16x8 v;
  v[0] = (bf16)a[0]; v[1] = (bf16)a[1]; v[2] = (bf16)a[2]; v[3] = (bf16)a[3];
  v[4] = (bf16)b[0]; v[5] = (bf16)b[1]; v[6] = (bf16)b[2]; v[7] = (bf16)b[3];
  ((bf16x8*)out)[i] = v;
}

__global__ void __launch_bounds__(256) wconv_all(
    const float* s0, bf16* d0, int n0,
    const float* s1, bf16* d1, int n1,
    const float* s2, bf16* d2, int n2,
    const float* s3, bf16* d3, int n3,
    const float* s4, bf16* d4, int n4,
    const float* s5, bf16* d5, int n5)
{
  int i = blockIdx.x * 256 + threadIdx.x;
  if (i < n0) { cvt8(s0, d0, i); return; } i -= n0;
  if (i < n1) { cvt8(s1, d1, i); return; } i -= n1;
  if (i < n2) { cvt8(s2, d2, i); return; } i -= n2;
  if (i < n3) { cvt8(s3, d3, i); return; } i -= n3;
  if (i < n4) { cvt8(s4, d4, i); return; } i -= n4;
  if (i < n5) { cvt8(s5, d5, i); return; }
}

// ---------------------------------------------------------------------------
__global__ void __launch_bounds__(256) gate_k(const bf16* __restrict__ mlp,
                                              const float* __restrict__ gw,
                                              float* __restrict__ probs)
{
  const int s = blockIdx.x, tid = threadIdx.x;
  float acc[8];
#pragma unroll
  for (int e = 0; e < 8; e++) acc[e] = 0.f;
  for (int c = tid; c < H_; c += 256) {
    float x = (float)mlp[(long)s * H_ + c];
#pragma unroll
    for (int e = 0; e < 8; e++) acc[e] += x * gw[e * H_ + c];
  }
  __shared__ float red[4][8];
#pragma unroll
  for (int e = 0; e < 8; e++) {
    float v = acc[e];
#pragma unroll
    for (int o = 32; o; o >>= 1) v += __shfl_xor(v, o, 64);
    if ((tid & 63) == 0) red[tid >> 6][e] = v;
  }
  __syncthreads();
  if (tid == 0) {
    float l[8]; float mx = -1e30f;
#pragma unroll
    for (int e = 0; e < 8; e++) { l[e] = red[0][e] + red[1][e] + red[2][e] + red[3][e]; mx = fmaxf(mx, l[e]); }
    float sum = 0.f;
#pragma unroll
    for (int e = 0; e < 8; e++) { l[e] = __expf(l[e] - mx); sum += l[e]; }
    float r = 1.f / sum;
#pragma unroll
    for (int e = 0; e < 8; e++) probs[(long)s * 8 + e] = l[e] * r;
  }
}

// ---------------------------------------------------------------------------
__global__ void prep_qkv_k(const bf16* __restrict__ q, const bf16* __restrict__ kv,
                           const float* __restrict__ ckv, const int* __restrict__ pos,
                           bf16* __restrict__ query, bf16* __restrict__ key,
                           bf16* __restrict__ vvT)
{
  const int s = blockIdx.x, h = blockIdx.y, d = threadIdx.x;
  const long qkOff = ((long)h * S_ + s) * QH_ + d;
  if (d < 64) {
    query[qkOff] = q[(long)s * H_ + h * QH_ + d];
    key[qkOff]   = kv[(long)s * H_ + h * QH_ + d];
    vvT[((long)h * 64 + d) * S_ + s] = kv[(long)s * H_ + h * QH_ + 64 + d];
  } else {
    const int i = d - 64;
    const float p = (float)pos[s];
    const float invf = powf(10000.f, -(float)(2 * (i & 31)) / 64.f);
    const float ang = p * invf;
    const float cc = cosf(ang), snv = sinf(ang);
    const float xq  = (float)q[(long)s * H_ + h * QH_ + 64 + i];
    const float xqr = (i < 32) ? -(float)q[(long)s * H_ + h * QH_ + 64 + i + 32]
                               :  (float)q[(long)s * H_ + h * QH_ + 64 + i - 32];
    query[qkOff] = (bf16)(xq * cc + xqr * snv);
    const float xk  = ckv[(long)s * 320 + 256 + i];
    const float xkr = (i < 32) ? -ckv[(long)s * 320 + 256 + i + 32]
                               :  ckv[(long)s * 320 + 256 + i - 32];
    key[qkOff] = (bf16)(xk * cc + xkr * snv);
  }
}

// ---------------------------------------------------------------------------
extern "C" void kernel_launch(void* const* d_in, const int* in_sizes, int n_in,
                              void* d_out, int out_size, void* d_ws, size_t ws_size,
                              hipStream_t stream)
{
  const int*   positions = (const int*)  d_in[0];
  const float* hidden    = (const float*)d_in[1];
  const float* ln1       = (const float*)d_in[2];
  const float* wq        = (const float*)d_in[3];
  const float* wkva      = (const float*)d_in[4];
  const float* lnkv      = (const float*)d_in[5];
  const float* wkvb      = (const float*)d_in[6];
  const float* wo        = (const float*)d_in[7];
  const float* ln2       = (const float*)d_in[8];
  const float* wg        = (const float*)d_in[9];
  const float* wfc1      = (const float*)d_in[10];
  const float* wfc2      = (const float*)d_in[11];
  float* out = (float*)d_out;

  char* wsb = (char*)d_ws;
  size_t off = 0;
  auto alloc = [&](size_t bytes) -> void* {
    void* p = wsb + off;
    off += (bytes + 255) & ~(size_t)255;
    return p;
  };
  bf16*  sa_in = (bf16*) alloc((size_t)S_ * H_ * 2);
  bf16*  qb    = (bf16*) alloc((size_t)S_ * H_ * 2);
  float* ckv   = (float*)alloc((size_t)S_ * 320 * 4);
  bf16*  ckvn  = (bf16*) alloc((size_t)S_ * KV_RANK_ * 2);
  bf16*  kvb   = (bf16*) alloc((size_t)S_ * H_ * 2);
  bf16*  query = (bf16*) alloc((size_t)NH_ * S_ * QH_ * 2);
  bf16*  key   = (bf16*) alloc((size_t)NH_ * S_ * QH_ * 2);
  bf16*  vvT   = (bf16*) alloc((size_t)NH_ * 64 * S_ * 2);
  bf16*  ctx   = (bf16*) alloc((size_t)S_ * NH_ * 64 * 2);
  bf16*  mlp   = (bf16*) alloc((size_t)S_ * H_ * 2);
  float* probs = (float*)alloc((size_t)S_ * 8 * 4);
  bf16*  hbuf  = (bf16*) alloc((size_t)S_ * EXP_ * INTER_ * 2);

  const size_t MBy = (size_t)1 << 20;
  const size_t rem = (ws_size > off) ? ws_size - off : 0;
  const size_t szMoeW = (size_t)EXP_ * INTER_ * H_ * 2;      // 46.1 MB each
  const bool cw = (rem >= 93 * MBy);

  bf16* fc1b = nullptr; bf16* fc2b = nullptr;
  if (cw) { fc1b = (bf16*)alloc(szMoeW); fc2b = (bf16*)alloc(szMoeW); }
  // attention weights (bf16) alias hbuf (dead until fc1; o_proj finishes first)
  bf16* wqb   = (bf16*)hbuf;
  bf16* wkvab = wqb   + (size_t)H_ * H_;
  bf16* wkvbb = wkvab + (size_t)320 * H_;
  bf16* wob   = wkvbb + (size_t)H_ * KV_RANK_;

  const float scale = 0.08838834764831845f;   // 128^-0.5

  rmsnorm_k<8><<<S_, 256, 0, stream>>>(hidden, ln1, sa_in, H_);

  if (cw) {
    const int n0 = H_*H_/8, n1 = 320*H_/8, n2 = H_*KV_RANK_/8,
              n3 = H_*NH_*64/8, n4 = EXP_*INTER_*H_/8, n5 = EXP_*INTER_*H_/8;
    const int tot = n0 + n1 + n2 + n3 + n4 + n5;
    wconv_all<<<(tot + 255)/256, 256, 0, stream>>>(
        wq, wqb, n0, wkva, wkvab, n1, wkvb, wkvbb, n2,
        wo, wob, n3, wfc1, fc1b, n4, wfc2, fc2b, n5);
  }

  // q_proj [2048x2048] + kv_a [2048x320], both K=2048, fused into one dispatch
  if (cw) {
    gemm_qkva<<<dim3(37, 32), 256, 0, stream>>>(sa_in, wqb, wkvab, qb, ckv);
  } else {
    gemm_bt<EPI_BF16, float, 64><<<dim3(32,32,1), 256, 0, stream>>>(
        sa_in, wq,  qb, hidden, S_, H_, H_, H_, H_, H_, 0,0,0,0,0, 0,0,0);
    gemm_bt<EPI_F32, float, 64><<<dim3(5,32,1), 256, 0, stream>>>(
        sa_in, wkva,  ckv, hidden, S_, 320, H_, H_, H_, 320, 0,0,0,0,0, 0,0,0);
  }

  rmsnorm_k<1><<<S_, 256, 0, stream>>>(ckv, lnkv, ckvn, 320);

  // kv_b [2048x2048, K=256]
  if (cw) gemm_bt<EPI_BF16, bf16, 64><<<dim3(32,32,1), 256, 0, stream>>>(
      ckvn, wkvbb, kvb, hidden, S_, H_, KV_RANK_, KV_RANK_, KV_RANK_, H_, 0,0,0,0,0, 0,0,0);
  else    gemm_bt<EPI_BF16, float, 64><<<dim3(32,32,1), 256, 0, stream>>>(
      ckvn, wkvb,  kvb, hidden, S_, H_, KV_RANK_, KV_RANK_, KV_RANK_, H_, 0,0,0,0,0, 0,0,0);

  prep2_k<<<S_, 256, 0, stream>>>(qb, kvb, ckv, positions, query, key, vvT);

  // fused causal attention -> ctx
  flash_k<<<dim3(NH_, S_/64), 256, 0, stream>>>(query, key, vvT, ctx, scale);

  // o_proj: out = hidden + ctx @ wo^T   (writes d_out directly)
  if (cw) gemm_bt<EPI_ADD, bf16, 64><<<dim3(32,32,1), 256, 0, stream>>>(
      ctx, wob, out, hidden, S_, H_, NH_*64, NH_*64, NH_*64, H_, 0,0,0,0, H_, 0,0,0);
  else    gemm_bt<EPI_ADD, float, 64><<<dim3(32,32,1), 256, 0, stream>>>(
      ctx, wo,  out, hidden, S_, H_, NH_*64, NH_*64, NH_*64, H_, 0,0,0,0, H_, 0,0,0);

  // fused post-attn RMSNorm + gate
  rmsgate_k<<<S_, 256, 0, stream>>>(out, ln2, wg, mlp, probs);

  // fc1: hbuf[s][e*1408+i] = silu(mlp @ fc1_w[e]^T) * probs[s][e]
  // XSWZ=1: 1408 wgs -> 176/XCD = exactly one expert per XCD.
  if (cw) gemm_bt<EPI_SILU, bf16, 128, 1><<<dim3(11,16,8), 256, 0, stream>>>(
      mlp, fc1b, hbuf, probs, S_, INTER_, H_, H_, H_, EXP_*INTER_,
      0, (long)INTER_*H_, INTER_, 1, 8, 0, 0, 0);
  else    gemm_bt<EPI_SILU, float, 128, 1><<<dim3(11,16,8), 256, 0, stream>>>(
      mlp, wfc1, hbuf, probs, S_, INTER_, H_, H_, H_, EXP_*INTER_,
      0, (long)INTER_*H_, INTER_, 1, 8, 0, 0, 0);

  // fc2: z=4, each z covers 2 experts flat-K (K=2816, kPerE hop), atomicAdd
  // fp32 into out. XSWZ=1: 1024 wgs -> 128/XCD contiguous chunk.
  if (cw) gemm_bt<EPI_ATOM, bf16, 128, 1><<<dim3(16,16,4), 256, 0, stream>>>(
      hbuf, fc2b, out, hidden, S_, H_, 2*INTER_, EXP_*INTER_, 0, H_,
      (long)(2*INTER_), 0, 0, 0, 0, INTER_, (long)H_*INTER_, 2);
  else    gemm_bt<EPI_ATOM, float, 128, 1><<<dim3(16,16,4), 256, 0, stream>>>(
      hbuf, wfc2, out, hidden, S_, H_, 2*INTER_, EXP_*INTER_, 0, H_,
      (long)(2*INTER_), 0, 0, 0, 0, INTER_, (long)H_*INTER_, 2);
}